// Round 1
// baseline (473.412 us; speedup 1.0000x reference)
//
#include <hip/hip_runtime.h>
#include <cstdint>

#define S_LEN 2048
#define D_MODEL 1024
#define NH 16
#define HDIM 64
#define BATCH 4

typedef __attribute__((ext_vector_type(8))) __bf16 bfrag;   // 8 bf16 = 4 VGPR
typedef __attribute__((ext_vector_type(4))) float ffrag;    // 4 f32 acc

__device__ __forceinline__ unsigned short f2bf(float f) {
    union { float f; uint32_t u; } v; v.f = f;
    uint32_t u = v.u;
    u += 0x7fff + ((u >> 16) & 1);   // round-to-nearest-even
    return (unsigned short)(u >> 16);
}

__device__ __forceinline__ bfrag ld_frag(const unsigned short* p) {
    union { uint4 u; bfrag b; } x;
    x.u = *(const uint4*)p;
    return x.b;
}

// ---------------- cast x (fp32 -> bf16), 8 elems/thread ----------------
__global__ __launch_bounds__(256) void cast_x_kernel(const float* __restrict__ x,
                                                     unsigned short* __restrict__ xb,
                                                     int n8) {
    int i = blockIdx.x * 256 + threadIdx.x;
    if (i >= n8) return;
    const float4* p = (const float4*)x + (size_t)i * 2;
    float4 a = p[0], b = p[1];
    union { unsigned short u[8]; uint4 v; } o;
    o.u[0]=f2bf(a.x); o.u[1]=f2bf(a.y); o.u[2]=f2bf(a.z); o.u[3]=f2bf(a.w);
    o.u[4]=f2bf(b.x); o.u[5]=f2bf(b.y); o.u[6]=f2bf(b.z); o.u[7]=f2bf(b.w);
    ((uint4*)xb)[i] = o.v;
}

// ------------- cast + transpose weights: Wt[mat][n][k] = W[k][n] -------------
__global__ __launch_bounds__(256) void transpose_w_kernel(const float* __restrict__ w0,
                                                          const float* __restrict__ w1,
                                                          const float* __restrict__ w2,
                                                          const float* __restrict__ w3,
                                                          unsigned short* __restrict__ wt) {
    __shared__ float tile[32][33];
    int mat = blockIdx.z;
    const float* w = (mat == 0) ? w0 : (mat == 1) ? w1 : (mat == 2) ? w2 : w3;
    int n0 = blockIdx.x * 32, k0 = blockIdx.y * 32;
    int tx = threadIdx.x, ty = threadIdx.y;  // 32 x 8
    for (int i = 0; i < 32; i += 8)
        tile[ty + i][tx] = w[(size_t)(k0 + ty + i) * D_MODEL + n0 + tx];
    __syncthreads();
    unsigned short* o = wt + (size_t)mat * D_MODEL * D_MODEL;
    for (int i = 0; i < 32; i += 8)
        o[(size_t)(n0 + ty + i) * D_MODEL + (k0 + tx)] = f2bf(tile[tx][ty + i]);
}

// ---------------- GEMM: C[M][N] = A[M][K=1024] * Bt[N][K]^T ----------------
// 128x128 tile, BK=32, 256 threads (4 waves, each 64x64 via 4x4 16x16x32 MFMAs)
#define LDA 40  // LDS row stride (elems): 80B, 16B-aligned, breaks bank conflicts

__global__ __launch_bounds__(256) void gemm_kernel(
    const unsigned short* __restrict__ A,
    const unsigned short* __restrict__ Bt,
    int mode,                                // 0 = QKV scatter, 1 = out + bias
    unsigned short* __restrict__ Qb,
    unsigned short* __restrict__ Kb,
    unsigned short* __restrict__ Vtb,
    float* __restrict__ Out,
    const float* __restrict__ bias) {
    __shared__ unsigned short As[128 * LDA];
    __shared__ unsigned short Bs[128 * LDA];
    int t = threadIdx.x;
    int m0 = blockIdx.y * 128;
    int n0 = blockIdx.x * 128;
    int wave = t >> 6, lane = t & 63;
    int quad = lane >> 4, lrow = lane & 15;
    int wm = (wave & 1) * 64, wn = (wave >> 1) * 64;

    ffrag acc[4][4];
    const ffrag fz = {0.f, 0.f, 0.f, 0.f};
    for (int i = 0; i < 4; i++)
        for (int j = 0; j < 4; j++) acc[i][j] = fz;

    int sr = t >> 2;          // 0..63
    int sc = (t & 3) * 8;     // 0,8,16,24
    const unsigned short* Ap = A + (size_t)(m0 + sr) * D_MODEL + sc;
    const unsigned short* Bp = Bt + (size_t)(n0 + sr) * D_MODEL + sc;

    for (int k0 = 0; k0 < D_MODEL; k0 += 32) {
        uint4 a0 = *(const uint4*)(Ap + k0);
        uint4 a1 = *(const uint4*)(Ap + k0 + (size_t)64 * D_MODEL);
        uint4 b0 = *(const uint4*)(Bp + k0);
        uint4 b1 = *(const uint4*)(Bp + k0 + (size_t)64 * D_MODEL);
        *(uint4*)&As[sr * LDA + sc] = a0;
        *(uint4*)&As[(sr + 64) * LDA + sc] = a1;
        *(uint4*)&Bs[sr * LDA + sc] = b0;
        *(uint4*)&Bs[(sr + 64) * LDA + sc] = b1;
        __syncthreads();
        bfrag af[4], bf[4];
        for (int mi = 0; mi < 4; mi++)
            af[mi] = ld_frag(&As[(wm + mi * 16 + lrow) * LDA + quad * 8]);
        for (int ni = 0; ni < 4; ni++)
            bf[ni] = ld_frag(&Bs[(wn + ni * 16 + lrow) * LDA + quad * 8]);
        for (int mi = 0; mi < 4; mi++)
            for (int ni = 0; ni < 4; ni++)
                acc[mi][ni] = __builtin_amdgcn_mfma_f32_16x16x32_bf16(af[mi], bf[ni], acc[mi][ni], 0, 0, 0);
        __syncthreads();
    }

    // epilogue — C element: row = m0+wm+mi*16+quad*4+r, col = n0+wn+ni*16+lrow
    for (int mi = 0; mi < 4; mi++) {
        int row = m0 + wm + mi * 16 + quad * 4;
        for (int ni = 0; ni < 4; ni++) {
            int col = n0 + wn + ni * 16 + lrow;
            for (int r = 0; r < 4; r++) {
                float v = acc[mi][ni][r];
                int m = row + r;
                if (mode == 0) {
                    int matid = col >> 10;
                    int nn = col & 1023;
                    int h = nn >> 6, d = nn & 63;
                    int b = m >> 11, s = m & 2047;
                    size_t bh = (size_t)(b * NH + h);
                    if (matid == 0)      Qb[(bh * S_LEN + s) * HDIM + d] = f2bf(v);
                    else if (matid == 1) Kb[(bh * S_LEN + s) * HDIM + d] = f2bf(v);
                    else                 Vtb[(bh * HDIM + d) * S_LEN + s] = f2bf(v);
                } else {
                    Out[(size_t)m * D_MODEL + col] = v + bias[col];
                }
            }
        }
    }
}

// ---------------- flash attention, causal ----------------
// grid (32 q-tiles, 64 bh), 256 threads. Each wave: 16 q-rows, full HD=64 out.
#define LDK 72  // padded LDS stride

__global__ __launch_bounds__(256) void attn_kernel(
    const unsigned short* __restrict__ Qb,
    const unsigned short* __restrict__ Kb,
    const unsigned short* __restrict__ Vtb,
    unsigned short* __restrict__ ctxb) {
    __shared__ unsigned short Ks[64 * LDK];
    __shared__ unsigned short Vs[64 * LDK];
    __shared__ unsigned short Ps[4 * 16 * LDK];
    int qt = blockIdx.x;   // 0..31
    int bh = blockIdx.y;   // 0..63
    int t = threadIdx.x;
    int wave = t >> 6, lane = t & 63;
    int quad = lane >> 4, lrow = lane & 15;

    int qbase = qt * 64 + wave * 16;
    const unsigned short* Qp = Qb + ((size_t)bh * S_LEN + qbase + lrow) * HDIM;
    bfrag qf0 = ld_frag(Qp + quad * 8);
    bfrag qf1 = ld_frag(Qp + quad * 8 + 32);

    ffrag acc_o[4];
    const ffrag fz = {0.f, 0.f, 0.f, 0.f};
    for (int i = 0; i < 4; i++) acc_o[i] = fz;
    float m_i[4], l_i[4];
    for (int r = 0; r < 4; r++) { m_i[r] = -1e30f; l_i[r] = 0.0f; }

    int sr = t >> 3;         // 0..31
    int sc = (t & 7) * 8;    // 0..56
    const unsigned short* Kp = Kb + (size_t)bh * S_LEN * HDIM;
    const unsigned short* Vp = Vtb + (size_t)bh * HDIM * S_LEN;
    unsigned short* Pw = &Ps[wave * 16 * LDK];

    for (int kt = 0; kt <= qt; kt++) {
        int kbase = kt * 64;
        __syncthreads();  // protect Ks/Vs/Ps of previous iteration
        *(uint4*)&Ks[sr * LDK + sc]        = *(const uint4*)(Kp + (size_t)(kbase + sr) * HDIM + sc);
        *(uint4*)&Ks[(sr + 32) * LDK + sc] = *(const uint4*)(Kp + (size_t)(kbase + sr + 32) * HDIM + sc);
        *(uint4*)&Vs[sr * LDK + sc]        = *(const uint4*)(Vp + (size_t)sr * S_LEN + kbase + sc);
        *(uint4*)&Vs[(sr + 32) * LDK + sc] = *(const uint4*)(Vp + (size_t)(sr + 32) * S_LEN + kbase + sc);
        __syncthreads();

        // S = Q K^T  (C layout: row=q=quad*4+r, col=key=lrow within 16-tile)
        ffrag sf[4];
        for (int ni = 0; ni < 4; ni++) {
            bfrag b0 = ld_frag(&Ks[(ni * 16 + lrow) * LDK + quad * 8]);
            bfrag b1 = ld_frag(&Ks[(ni * 16 + lrow) * LDK + quad * 8 + 32]);
            ffrag s = fz;
            s = __builtin_amdgcn_mfma_f32_16x16x32_bf16(qf0, b0, s, 0, 0, 0);
            s = __builtin_amdgcn_mfma_f32_16x16x32_bf16(qf1, b1, s, 0, 0, 0);
            sf[ni] = s;
        }

        // scale + causal mask + row max
        float rmax[4];
        for (int r = 0; r < 4; r++) rmax[r] = -1e30f;
        int qrow0 = qbase + quad * 4;
        for (int ni = 0; ni < 4; ni++) {
            int key = kbase + ni * 16 + lrow;
            for (int r = 0; r < 4; r++) {
                float v = sf[ni][r] * 0.125f;
                v = (key <= qrow0 + r) ? v : -1e30f;
                sf[ni][r] = v;
                rmax[r] = fmaxf(rmax[r], v);
            }
        }
        for (int off = 8; off >= 1; off >>= 1)
            for (int r = 0; r < 4; r++)
                rmax[r] = fmaxf(rmax[r], __shfl_xor(rmax[r], off));

        float alpha[4], rsum[4];
        for (int r = 0; r < 4; r++) {
            float mnew = fmaxf(m_i[r], rmax[r]);
            alpha[r] = __expf(m_i[r] - mnew);
            m_i[r] = mnew;
            rsum[r] = 0.0f;
        }
        for (int ni = 0; ni < 4; ni++)
            for (int r = 0; r < 4; r++) {
                float p = __expf(sf[ni][r] - m_i[r]);
                sf[ni][r] = p;
                rsum[r] += p;
            }
        for (int off = 8; off >= 1; off >>= 1)
            for (int r = 0; r < 4; r++)
                rsum[r] += __shfl_xor(rsum[r], off);
        for (int r = 0; r < 4; r++) l_i[r] = l_i[r] * alpha[r] + rsum[r];
        for (int ni = 0; ni < 4; ni++)
            for (int r = 0; r < 4; r++) acc_o[ni][r] *= alpha[r];

        // P (C layout) -> LDS -> A-operand layout
        for (int ni = 0; ni < 4; ni++)
            for (int r = 0; r < 4; r++)
                Pw[(quad * 4 + r) * LDK + ni * 16 + lrow] = f2bf(sf[ni][r]);
        __syncthreads();

        bfrag ap0 = ld_frag(&Pw[lrow * LDK + quad * 8]);
        bfrag ap1 = ld_frag(&Pw[lrow * LDK + quad * 8 + 32]);
        for (int ni = 0; ni < 4; ni++) {
            bfrag v0 = ld_frag(&Vs[(ni * 16 + lrow) * LDK + quad * 8]);
            bfrag v1 = ld_frag(&Vs[(ni * 16 + lrow) * LDK + quad * 8 + 32]);
            acc_o[ni] = __builtin_amdgcn_mfma_f32_16x16x32_bf16(ap0, v0, acc_o[ni], 0, 0, 0);
            acc_o[ni] = __builtin_amdgcn_mfma_f32_16x16x32_bf16(ap1, v1, acc_o[ni], 0, 0, 0);
        }
    }

    // epilogue: ctx[b, q, h*64+d]
    int b = bh >> 4, h = bh & 15;
    for (int ni = 0; ni < 4; ni++) {
        for (int r = 0; r < 4; r++) {
            int q = qbase + quad * 4 + r;
            int dcol = h * HDIM + ni * 16 + lrow;
            float v = acc_o[ni][r] / l_i[r];
            ctxb[((size_t)b * S_LEN + q) * D_MODEL + dcol] = f2bf(v);
        }
    }
}

extern "C" void kernel_launch(void* const* d_in, const int* in_sizes, int n_in,
                              void* d_out, int out_size, void* d_ws, size_t ws_size,
                              hipStream_t stream) {
    const float* x   = (const float*)d_in[0];
    const float* W_q = (const float*)d_in[1];
    const float* W_k = (const float*)d_in[2];
    const float* W_v = (const float*)d_in[3];
    const float* W_o = (const float*)d_in[4];
    const float* b_o = (const float*)d_in[5];
    float* out = (float*)d_out;

    // workspace carve (elems, ushort)
    unsigned short* xb   = (unsigned short*)d_ws;                    // 8192*1024
    unsigned short* Wt   = xb + (size_t)8192 * 1024;                 // 4*1024*1024
    unsigned short* Qb   = Wt + (size_t)4 * 1024 * 1024;             // 64*2048*64
    unsigned short* Kb   = Qb + (size_t)64 * 2048 * 64;
    unsigned short* Vtb  = Kb + (size_t)64 * 2048 * 64;
    unsigned short* ctxb = Vtb + (size_t)64 * 2048 * 64;             // 8192*1024
    unsigned short* Wto  = Wt + (size_t)3 * 1024 * 1024;

    int n8 = (BATCH * S_LEN * D_MODEL) / 8;  // 1048576
    cast_x_kernel<<<n8 / 256, 256, 0, stream>>>(x, xb, n8);
    transpose_w_kernel<<<dim3(32, 32, 4), dim3(32, 8), 0, stream>>>(W_q, W_k, W_v, W_o, Wt);
    // QKV: M=8192, N=3072
    gemm_kernel<<<dim3(24, 64), 256, 0, stream>>>(xb, Wt, 0, Qb, Kb, Vtb, nullptr, nullptr);
    // attention
    attn_kernel<<<dim3(32, 64), 256, 0, stream>>>(Qb, Kb, Vtb, ctxb);
    // out proj: M=8192, N=1024, + bias
    gemm_kernel<<<dim3(8, 64), 256, 0, stream>>>(ctxb, Wto, 1, nullptr, nullptr, nullptr, out, b_o);
}